// Round 3
// baseline (522.218 us; speedup 1.0000x reference)
//
#include <hip/hip_runtime.h>

#define D 128
#define BIN_SHIFT 4   // 16 dst-nodes per bin

// round-to-nearest-even fp32 -> bf16 bits
__device__ __forceinline__ unsigned short f2bf(float f) {
  unsigned int u = __float_as_uint(f);
  return (unsigned short)((u + 0x7FFFu + ((u >> 16) & 1u)) >> 16);
}

// ---------------- setup kernels ----------------

__global__ __launch_bounds__(256) void k_init(int* cnt, int N, float* accB, int* cntB, int B) {
  int i = blockIdx.x * 256 + threadIdx.x;
  if (i < N) cnt[i] = 1;                 // self-loop
  if (i < B) { accB[i] = 0.f; cntB[i] = 0; }
}

__global__ __launch_bounds__(256) void k_count(const int* __restrict__ ei, int E,
                                               const int* __restrict__ batch, int N,
                                               int* cnt, int* cntB) {
  int i = blockIdx.x * 256 + threadIdx.x;
  if (i < E) {
    atomicAdd(&cnt[ei[E + i]], 1);       // dst = row 1 of edge_index
  } else if (i < E + N) {
    atomicAdd(&cntB[batch[i - E]], 1);   // nodes per graph
  }
}

__global__ __launch_bounds__(256) void k_dinv(const int* __restrict__ cnt, float* dinv, int N) {
  int i = blockIdx.x * 256 + threadIdx.x;
  if (i < N) dinv[i] = rsqrtf((float)cnt[i]);   // deg >= 1 always
}

// exclusive scan of cnt -> offs, cursor; offs[N]=total; binCur[b]=offs[b*16].
__global__ __launch_bounds__(1024) void k_scan(const int* __restrict__ cnt,
                                               int* offs, int* cursor, int N,
                                               int* binCur, int NB) {
  __shared__ int wsum[16];
  __shared__ int carry_s;
  int tid = threadIdx.x, wid = tid >> 6, lane = tid & 63;
  if (tid == 0) carry_s = 0;
  __syncthreads();
  for (int base = 0; base < N; base += 1024) {
    int i = base + tid;
    int v = (i < N) ? cnt[i] : 0;
    int x = v;                                   // inclusive wave scan
    #pragma unroll
    for (int s = 1; s < 64; s <<= 1) {
      int t = __shfl_up(x, s);
      if (lane >= s) x += t;
    }
    if (lane == 63) wsum[wid] = x;
    __syncthreads();
    int woff = 0;
    for (int w = 0; w < wid; ++w) woff += wsum[w];
    int carry = carry_s;
    if (i < N) { int e = carry + woff + x - v; offs[i] = e; cursor[i] = e; }
    __syncthreads();
    if (tid == 1023) carry_s = carry + woff + x;
  }
  __syncthreads();
  if (tid == 0) offs[N] = carry_s;
  // bin cursors: offs[] fully written before the barrier above; (NB-1)<<4 < N
  for (int b = tid; b < NB; b += 1024) binCur[b] = offs[b << BIN_SHIFT];
}

// phase 1: append packed {src | dst<<14} into per-bin regions (requires N < 16384)
__global__ __launch_bounds__(256) void k_bin(const int* __restrict__ ei, int E, int N,
                                             int* binCur, int* __restrict__ pk) {
  int i = blockIdx.x * 256 + threadIdx.x;
  if (i < E) {
    int s = ei[i];
    int d = ei[E + i];
    int p = atomicAdd(&binCur[d >> BIN_SHIFT], 1);
    pk[p] = s | (d << 14);
  } else if (i < E + N) {
    int n_ = i - E;       // self-loop
    int p = atomicAdd(&binCur[n_ >> BIN_SHIFT], 1);
    pk[p] = n_ | (n_ << 14);
  }
}

// phase 2: coalesced read of bins, scatter into per-dst segments (L2-local window)
__global__ __launch_bounds__(256) void k_place(const int* __restrict__ pk, int M,
                                               const float* __restrict__ dinv,
                                               int* cursor, float2* __restrict__ epair) {
  int p = blockIdx.x * 256 + threadIdx.x;
  if (p >= M) return;
  int rec = pk[p];
  int s = rec & 0x3FFF;
  int d = rec >> 14;
  float w = dinv[s] * dinv[d];
  int q = atomicAdd(&cursor[d], 1);
  float2 ew; ew.x = __int_as_float(s); ew.y = w;
  epair[q] = ew;
}

// ---------------- GEMM: C[N x 128](bf16) = A[N x 128](f32) @ W[128 x 128](f32) ----------------
__global__ __launch_bounds__(256) void k_gemm(const float* __restrict__ A,
                                              const float* __restrict__ W,
                                              unsigned short* __restrict__ C, int N) {
  __shared__ float As[32][36];
  __shared__ float Ws[32][128];
  int tid = threadIdx.x;
  int tx = tid & 31;
  int ty = tid >> 5;
  int r0 = blockIdx.x * 32;
  float acc[4][4] = {};

  for (int k0 = 0; k0 < 128; k0 += 32) {
    for (int i = tid; i < 1024; i += 256) {
      int kk = i >> 5, j4 = i & 31;
      float4 w = *(const float4*)(W + (size_t)(k0 + kk) * 128 + j4 * 4);
      *(float4*)(&Ws[kk][j4 * 4]) = w;
    }
    {
      int r = tid >> 3, k4 = tid & 7;
      int row = r0 + r;
      float4 a = make_float4(0.f, 0.f, 0.f, 0.f);
      if (row < N) a = *(const float4*)(A + (size_t)row * 128 + k0 + k4 * 4);
      As[k4 * 4 + 0][r] = a.x;
      As[k4 * 4 + 1][r] = a.y;
      As[k4 * 4 + 2][r] = a.z;
      As[k4 * 4 + 3][r] = a.w;
    }
    __syncthreads();
    #pragma unroll
    for (int k = 0; k < 32; ++k) {
      float4 a = *(const float4*)(&As[k][ty * 4]);
      float4 b = *(const float4*)(&Ws[k][tx * 4]);
      float av[4] = {a.x, a.y, a.z, a.w};
      float bv[4] = {b.x, b.y, b.z, b.w};
      #pragma unroll
      for (int i = 0; i < 4; ++i)
        #pragma unroll
        for (int j = 0; j < 4; ++j)
          acc[i][j] = fmaf(av[i], bv[j], acc[i][j]);
    }
    __syncthreads();
  }
  #pragma unroll
  for (int i = 0; i < 4; ++i) {
    int row = r0 + ty * 4 + i;
    if (row < N) {
      ushort4 o;
      o.x = f2bf(acc[i][0]); o.y = f2bf(acc[i][1]);
      o.z = f2bf(acc[i][2]); o.w = f2bf(acc[i][3]);
      *(ushort4*)(C + (size_t)row * 128 + tx * 4) = o;
    }
  }
}

// ---------------- aggregation: one wave per node, shfl-broadcast indices, bf16 rows ----------------
__device__ __forceinline__ void agg_core(const unsigned short* __restrict__ t,
                                         const float2* __restrict__ epair,
                                         int beg, int end, int lane,
                                         float& ax, float& ay) {
  for (int c = beg; c < end; c += 64) {
    int m = end - c;
    int cn = m < 64 ? m : 64;
    float2 ep = make_float2(0.f, 0.f);
    if (lane < cn) ep = epair[c + lane];
    int   s_l = __float_as_int(ep.x);
    float w_l = ep.y;
    int e = 0;
    for (; e + 8 <= cn; e += 8) {
      #pragma unroll
      for (int u = 0; u < 8; ++u) {
        int   s = __shfl(s_l, e + u);
        float w = __shfl(w_l, e + u);
        unsigned int v = *(const unsigned int*)(t + ((size_t)s << 7) + (lane << 1));
        ax = fmaf(w, __uint_as_float(v << 16), ax);
        ay = fmaf(w, __uint_as_float(v & 0xFFFF0000u), ay);
      }
    }
    for (; e < cn; ++e) {
      int   s = __shfl(s_l, e);
      float w = __shfl(w_l, e);
      unsigned int v = *(const unsigned int*)(t + ((size_t)s << 7) + (lane << 1));
      ax = fmaf(w, __uint_as_float(v << 16), ax);
      ay = fmaf(w, __uint_as_float(v & 0xFFFF0000u), ay);
    }
  }
}

__global__ __launch_bounds__(256) void k_agg(const unsigned short* __restrict__ t,
                                             const float2* __restrict__ epair,
                                             const int* __restrict__ offs,
                                             const float* __restrict__ bias,
                                             float* __restrict__ hout, int N, int relu) {
  int node = blockIdx.x * 4 + (threadIdx.x >> 6);
  int lane = threadIdx.x & 63;
  if (node >= N) return;
  float ax = 0.f, ay = 0.f;
  agg_core(t, epair, offs[node], offs[node + 1], lane, ax, ay);
  float2 b = *(const float2*)(bias + lane * 2);
  ax += b.x; ay += b.y;
  if (relu) { ax = fmaxf(ax, 0.f); ay = fmaxf(ay, 0.f); }
  *(float2*)(hout + (size_t)node * 128 + lane * 2) = make_float2(ax, ay);
}

__global__ __launch_bounds__(256) void k_agg_pool(const unsigned short* __restrict__ t,
                                                  const float2* __restrict__ epair,
                                                  const int* __restrict__ offs,
                                                  const float* __restrict__ bias,
                                                  const float* __restrict__ Wp,
                                                  const int* __restrict__ batch,
                                                  float* accB, int N) {
  int node = blockIdx.x * 4 + (threadIdx.x >> 6);
  int lane = threadIdx.x & 63;
  if (node >= N) return;
  float ax = 0.f, ay = 0.f;
  agg_core(t, epair, offs[node], offs[node + 1], lane, ax, ay);
  float2 b = *(const float2*)(bias + lane * 2);
  float2 wp = *(const float2*)(Wp + lane * 2);
  float p = (ax + b.x) * wp.x + (ay + b.y) * wp.y;
  #pragma unroll
  for (int s = 32; s; s >>= 1) p += __shfl_xor(p, s);
  if (lane == 0) atomicAdd(&accB[batch[node]], p);
}

__global__ __launch_bounds__(64) void k_final(const float* __restrict__ accB,
                                              const int* __restrict__ cntB,
                                              const float* __restrict__ bp,
                                              float* out, int B) {
  int b = blockIdx.x * 64 + threadIdx.x;
  if (b < B) {
    float c = (float)(cntB[b] > 1 ? cntB[b] : 1);
    out[b] = accB[b] / c + bp[0];
  }
}

// ---------------- launch ----------------

extern "C" void kernel_launch(void* const* d_in, const int* in_sizes, int n_in,
                              void* d_out, int out_size, void* d_ws, size_t ws_size,
                              hipStream_t stream) {
  const float* x    = (const float*)d_in[0];
  const int*   ei   = (const int*)d_in[1];
  const int*   batch= (const int*)d_in[2];
  const float* W1   = (const float*)d_in[3];
  const float* b1   = (const float*)d_in[4];
  const float* W2   = (const float*)d_in[5];
  const float* b2   = (const float*)d_in[6];
  const float* W3   = (const float*)d_in[7];
  const float* b3   = (const float*)d_in[8];
  const float* Wp   = (const float*)d_in[9];
  const float* bp   = (const float*)d_in[10];
  float* out = (float*)d_out;

  int N = in_sizes[0] / D;
  int E = in_sizes[1] / 2;
  int B = out_size;
  int M = E + N;
  int NB = (N + (1 << BIN_SHIFT) - 1) >> BIN_SHIFT;

  char* p = (char*)d_ws;
  float2* epair  = (float2*)p;          p += (size_t)M * 8;
  float* hbuf    = (float*)p;           p += (size_t)N * D * 4;
  unsigned short* tbuf = (unsigned short*)p; p += (size_t)N * D * 2;
  int*   pk      = (int*)p;             p += (size_t)M * 4;
  int*   cnt     = (int*)p;             p += (size_t)N * 4;
  int*   offs    = (int*)p;             p += (size_t)(N + 1) * 4;
  int*   cursor  = (int*)p;             p += (size_t)N * 4;
  int*   binCur  = (int*)p;             p += (size_t)NB * 4;
  float* dinv    = (float*)p;           p += (size_t)N * 4;
  float* accB    = (float*)p;           p += (size_t)B * 4;
  int*   cntB    = (int*)p;             p += (size_t)B * 4;

  int gN  = (N + 255) / 256;
  int gEN = (E + N + 255) / 256;
  int gM  = (M + 255) / 256;
  int gG  = (N + 31) / 32;
  int gA  = (N + 3) / 4;

  k_init <<<gN, 256, 0, stream>>>(cnt, N, accB, cntB, B);
  k_count<<<gEN, 256, 0, stream>>>(ei, E, batch, N, cnt, cntB);
  k_dinv <<<gN, 256, 0, stream>>>(cnt, dinv, N);
  k_scan <<<1, 1024, 0, stream>>>(cnt, offs, cursor, N, binCur, NB);
  k_bin  <<<gEN, 256, 0, stream>>>(ei, E, N, binCur, pk);
  k_place<<<gM, 256, 0, stream>>>(pk, M, dinv, cursor, epair);

  k_gemm<<<gG, 256, 0, stream>>>(x, W1, tbuf, N);
  k_agg <<<gA, 256, 0, stream>>>(tbuf, epair, offs, b1, hbuf, N, 1);
  k_gemm<<<gG, 256, 0, stream>>>(hbuf, W2, tbuf, N);
  k_agg <<<gA, 256, 0, stream>>>(tbuf, epair, offs, b2, hbuf, N, 1);
  k_gemm<<<gG, 256, 0, stream>>>(hbuf, W3, tbuf, N);
  k_agg_pool<<<gA, 256, 0, stream>>>(tbuf, epair, offs, b3, Wp, batch, accB, N);
  k_final<<<(B + 63) / 64, 64, 0, stream>>>(accB, cntB, bp, out, B);
}

// Round 4
// 342.757 us; speedup vs baseline: 1.5236x; 1.5236x over previous
//
#include <hip/hip_runtime.h>

#define D 128

// round-to-nearest-even fp32 -> bf16 bits
__device__ __forceinline__ unsigned short f2bf(float f) {
  unsigned int u = __float_as_uint(f);
  return (unsigned short)((u + 0x7FFFu + ((u >> 16) & 1u)) >> 16);
}

// ---------------- setup kernels ----------------

__global__ __launch_bounds__(256) void k_init(int* cnt, int N, float* accB, int* cntB, int B) {
  int i = blockIdx.x * 256 + threadIdx.x;
  if (i < N) cnt[i] = 1;                 // self-loop
  if (i < B) { accB[i] = 0.f; cntB[i] = 0; }
}

// degree count + per-graph node count + pack messages into pk[i] = src | dst<<14
// (requires N < 16384; here N = 10000)
__global__ __launch_bounds__(256) void k_count(const int* __restrict__ ei, int E,
                                               const int* __restrict__ batch, int N,
                                               int* cnt, int* cntB, int* __restrict__ pk) {
  int i = blockIdx.x * 256 + threadIdx.x;
  if (i < E) {
    int s = ei[i];
    int d = ei[E + i];
    pk[i] = s | (d << 14);
    atomicAdd(&cnt[d], 1);
  } else if (i < E + N) {
    int n_ = i - E;                       // self-loop message
    pk[i] = n_ | (n_ << 14);
    atomicAdd(&cntB[batch[n_]], 1);
  }
}

__global__ __launch_bounds__(256) void k_dinv(const int* __restrict__ cnt, float* dinv, int N) {
  int i = blockIdx.x * 256 + threadIdx.x;
  if (i < N) dinv[i] = rsqrtf((float)cnt[i]);   // deg >= 1 always
}

// exclusive scan of cnt -> offs, cursor; offs[N]=total. Single block.
__global__ __launch_bounds__(1024) void k_scan(const int* __restrict__ cnt,
                                               int* offs, int* cursor, int N) {
  __shared__ int wsum[16];
  __shared__ int carry_s;
  int tid = threadIdx.x, wid = tid >> 6, lane = tid & 63;
  if (tid == 0) carry_s = 0;
  __syncthreads();
  for (int base = 0; base < N; base += 1024) {
    int i = base + tid;
    int v = (i < N) ? cnt[i] : 0;
    int x = v;                                   // inclusive wave scan
    #pragma unroll
    for (int s = 1; s < 64; s <<= 1) {
      int t = __shfl_up(x, s);
      if (lane >= s) x += t;
    }
    if (lane == 63) wsum[wid] = x;
    __syncthreads();
    int woff = 0;
    for (int w = 0; w < wid; ++w) woff += wsum[w];
    int carry = carry_s;
    if (i < N) { int e = carry + woff + x - v; offs[i] = e; cursor[i] = e; }
    __syncthreads();
    if (tid == 1023) carry_s = carry + woff + x;
  }
  __syncthreads();
  if (tid == 0) offs[N] = carry_s;
}

// XCD-local CSR fill: block's presumed XCD = blockIdx&7 handles dst range
// [part*N/8, (part+1)*N/8): every epair cache line is written by one XCD only,
// stays L2-resident (~650 KB/XCD), full lines -> no partial-line write-back storm.
__global__ __launch_bounds__(256) void k_fill(const int* __restrict__ pk, int M, int N,
                                              const float* __restrict__ dinv,
                                              int* cursor, float2* __restrict__ epair) {
  int part = blockIdx.x & 7;
  int j    = blockIdx.x >> 3;
  int nj   = gridDim.x >> 3;
  int lo = (int)((long long)part * N >> 3);
  int hi = (int)((long long)(part + 1) * N >> 3);
  for (int i = j * 256 + threadIdx.x; i < M; i += nj * 256) {
    int rec = pk[i];
    int d = rec >> 14;
    if (d < lo || d >= hi) continue;
    int s = rec & 0x3FFF;
    float w = dinv[s] * dinv[d];
    int q = atomicAdd(&cursor[d], 1);
    epair[q] = make_float2(__int_as_float(s), w);
  }
}

// ---------------- GEMM: C[N x 128](bf16) = A[N x 128](f32) @ W[128 x 128](f32) ----------------
__global__ __launch_bounds__(256) void k_gemm(const float* __restrict__ A,
                                              const float* __restrict__ W,
                                              unsigned short* __restrict__ C, int N) {
  __shared__ float As[32][36];
  __shared__ float Ws[32][128];
  int tid = threadIdx.x;
  int tx = tid & 31;
  int ty = tid >> 5;
  int r0 = blockIdx.x * 32;
  float acc[4][4] = {};

  for (int k0 = 0; k0 < 128; k0 += 32) {
    for (int i = tid; i < 1024; i += 256) {
      int kk = i >> 5, j4 = i & 31;
      float4 w = *(const float4*)(W + (size_t)(k0 + kk) * 128 + j4 * 4);
      *(float4*)(&Ws[kk][j4 * 4]) = w;
    }
    {
      int r = tid >> 3, k4 = tid & 7;
      int row = r0 + r;
      float4 a = make_float4(0.f, 0.f, 0.f, 0.f);
      if (row < N) a = *(const float4*)(A + (size_t)row * 128 + k0 + k4 * 4);
      As[k4 * 4 + 0][r] = a.x;
      As[k4 * 4 + 1][r] = a.y;
      As[k4 * 4 + 2][r] = a.z;
      As[k4 * 4 + 3][r] = a.w;
    }
    __syncthreads();
    #pragma unroll
    for (int k = 0; k < 32; ++k) {
      float4 a = *(const float4*)(&As[k][ty * 4]);
      float4 b = *(const float4*)(&Ws[k][tx * 4]);
      float av[4] = {a.x, a.y, a.z, a.w};
      float bv[4] = {b.x, b.y, b.z, b.w};
      #pragma unroll
      for (int i = 0; i < 4; ++i)
        #pragma unroll
        for (int j = 0; j < 4; ++j)
          acc[i][j] = fmaf(av[i], bv[j], acc[i][j]);
    }
    __syncthreads();
  }
  #pragma unroll
  for (int i = 0; i < 4; ++i) {
    int row = r0 + ty * 4 + i;
    if (row < N) {
      ushort4 o;
      o.x = f2bf(acc[i][0]); o.y = f2bf(acc[i][1]);
      o.z = f2bf(acc[i][2]); o.w = f2bf(acc[i][3]);
      *(ushort4*)(C + (size_t)row * 128 + tx * 4) = o;
    }
  }
}

// ---------------- aggregation ----------------
// One wave per node. Edge metadata loaded at a wave-uniform address (node forced
// into SGPR via readfirstlane) -> one 8B broadcast load per edge, no bpermute,
// no LDS. Two-phase 16-deep unroll: 16 metadata loads in flight, then 16
// independent bf16-row gathers.
__device__ __forceinline__ void agg_core(const unsigned short* __restrict__ t,
                                         const float2* __restrict__ epair,
                                         int beg, int end, int lane,
                                         float& ax, float& ay) {
  int e = beg;
  for (; e + 16 <= end; e += 16) {
    float2 ep[16];
    #pragma unroll
    for (int u = 0; u < 16; ++u) ep[u] = epair[e + u];
    #pragma unroll
    for (int u = 0; u < 16; ++u) {
      int   s = __float_as_int(ep[u].x);
      float w = ep[u].y;
      unsigned int v = *(const unsigned int*)(t + ((size_t)s << 7) + (lane << 1));
      ax = fmaf(w, __uint_as_float(v << 16), ax);
      ay = fmaf(w, __uint_as_float(v & 0xFFFF0000u), ay);
    }
  }
  for (; e < end; ++e) {
    float2 ep = epair[e];
    int   s = __float_as_int(ep.x);
    float w = ep.y;
    unsigned int v = *(const unsigned int*)(t + ((size_t)s << 7) + (lane << 1));
    ax = fmaf(w, __uint_as_float(v << 16), ax);
    ay = fmaf(w, __uint_as_float(v & 0xFFFF0000u), ay);
  }
}

__global__ __launch_bounds__(256) void k_agg(const unsigned short* __restrict__ t,
                                             const float2* __restrict__ epair,
                                             const int* __restrict__ offs,
                                             const float* __restrict__ bias,
                                             float* __restrict__ hout, int N, int relu) {
  int node = __builtin_amdgcn_readfirstlane(blockIdx.x * 4 + (threadIdx.x >> 6));
  int lane = threadIdx.x & 63;
  if (node >= N) return;
  int beg = offs[node], end = offs[node + 1];
  float ax = 0.f, ay = 0.f;
  agg_core(t, epair, beg, end, lane, ax, ay);
  float2 b = *(const float2*)(bias + lane * 2);
  ax += b.x; ay += b.y;
  if (relu) { ax = fmaxf(ax, 0.f); ay = fmaxf(ay, 0.f); }
  *(float2*)(hout + (size_t)node * 128 + lane * 2) = make_float2(ax, ay);
}

__global__ __launch_bounds__(256) void k_agg_pool(const unsigned short* __restrict__ t,
                                                  const float2* __restrict__ epair,
                                                  const int* __restrict__ offs,
                                                  const float* __restrict__ bias,
                                                  const float* __restrict__ Wp,
                                                  const int* __restrict__ batch,
                                                  float* accB, int N) {
  int node = __builtin_amdgcn_readfirstlane(blockIdx.x * 4 + (threadIdx.x >> 6));
  int lane = threadIdx.x & 63;
  if (node >= N) return;
  int beg = offs[node], end = offs[node + 1];
  float ax = 0.f, ay = 0.f;
  agg_core(t, epair, beg, end, lane, ax, ay);
  float2 b = *(const float2*)(bias + lane * 2);
  float2 wp = *(const float2*)(Wp + lane * 2);
  float p = (ax + b.x) * wp.x + (ay + b.y) * wp.y;
  #pragma unroll
  for (int s = 32; s; s >>= 1) p += __shfl_xor(p, s);
  if (lane == 0) atomicAdd(&accB[batch[node]], p);
}

__global__ __launch_bounds__(64) void k_final(const float* __restrict__ accB,
                                              const int* __restrict__ cntB,
                                              const float* __restrict__ bp,
                                              float* out, int B) {
  int b = blockIdx.x * 64 + threadIdx.x;
  if (b < B) {
    float c = (float)(cntB[b] > 1 ? cntB[b] : 1);
    out[b] = accB[b] / c + bp[0];
  }
}

// ---------------- launch ----------------

extern "C" void kernel_launch(void* const* d_in, const int* in_sizes, int n_in,
                              void* d_out, int out_size, void* d_ws, size_t ws_size,
                              hipStream_t stream) {
  const float* x    = (const float*)d_in[0];
  const int*   ei   = (const int*)d_in[1];
  const int*   batch= (const int*)d_in[2];
  const float* W1   = (const float*)d_in[3];
  const float* b1   = (const float*)d_in[4];
  const float* W2   = (const float*)d_in[5];
  const float* b2   = (const float*)d_in[6];
  const float* W3   = (const float*)d_in[7];
  const float* b3   = (const float*)d_in[8];
  const float* Wp   = (const float*)d_in[9];
  const float* bp   = (const float*)d_in[10];
  float* out = (float*)d_out;

  int N = in_sizes[0] / D;
  int E = in_sizes[1] / 2;
  int B = out_size;
  int M = E + N;

  char* p = (char*)d_ws;
  float2* epair  = (float2*)p;          p += (size_t)M * 8;
  float* hbuf    = (float*)p;           p += (size_t)N * D * 4;
  unsigned short* tbuf = (unsigned short*)p; p += (size_t)N * D * 2;
  int*   pk      = (int*)p;             p += (size_t)M * 4;
  int*   cnt     = (int*)p;             p += (size_t)N * 4;
  int*   offs    = (int*)p;             p += (size_t)(N + 1) * 4;
  int*   cursor  = (int*)p;             p += (size_t)N * 4;
  float* dinv    = (float*)p;           p += (size_t)N * 4;
  float* accB    = (float*)p;           p += (size_t)B * 4;
  int*   cntB    = (int*)p;             p += (size_t)B * 4;

  int gN  = (N + 255) / 256;
  int gEN = (E + N + 255) / 256;
  int gG  = (N + 31) / 32;
  int gA  = (N + 3) / 4;

  k_init <<<gN, 256, 0, stream>>>(cnt, N, accB, cntB, B);
  k_count<<<gEN, 256, 0, stream>>>(ei, E, batch, N, cnt, cntB, pk);
  k_dinv <<<gN, 256, 0, stream>>>(cnt, dinv, N);
  k_scan <<<1, 1024, 0, stream>>>(cnt, offs, cursor, N);
  k_fill <<<2048, 256, 0, stream>>>(pk, M, N, dinv, cursor, epair);

  k_gemm<<<gG, 256, 0, stream>>>(x, W1, tbuf, N);
  k_agg <<<gA, 256, 0, stream>>>(tbuf, epair, offs, b1, hbuf, N, 1);
  k_gemm<<<gG, 256, 0, stream>>>(hbuf, W2, tbuf, N);
  k_agg <<<gA, 256, 0, stream>>>(tbuf, epair, offs, b2, hbuf, N, 1);
  k_gemm<<<gG, 256, 0, stream>>>(hbuf, W3, tbuf, N);
  k_agg_pool<<<gA, 256, 0, stream>>>(tbuf, epair, offs, b3, Wp, batch, accB, N);
  k_final<<<(B + 63) / 64, 64, 0, stream>>>(accB, cntB, bp, out, B);
}